// Round 8
// baseline (239.815 us; speedup 1.0000x reference)
//
#include <hip/hip_runtime.h>

#define DIM 128
#define CAP 48

typedef _Float16 half8 __attribute__((ext_vector_type(8)));
typedef float f32x4 __attribute__((ext_vector_type(4)));

__device__ __forceinline__ float lrelu(float v) { return v > 0.f ? v : 0.01f * v; }

// Unscaled gather (hs2 rows are pre-scaled): 8-wide bursts, dead slots -> zero row zr.
__device__ __forceinline__ void gather_sum(
    const _Float16* __restrict__ H, const int* __restrict__ sl,
    int cnt, int g, int zr, float a[8]) {
    int c16 = cnt < 16 ? cnt : 16;
    int sidb = (g < c16) ? sl[g] : zr;
    half8 v[8];
#pragma unroll
    for (int j = 0; j < 8; ++j) {
        int s = __shfl(sidb, j, 16);
        v[j] = *(const half8*)&H[(size_t)s * DIM + g * 8];
    }
#pragma unroll
    for (int j = 0; j < 8; ++j)
#pragma unroll
        for (int e = 0; e < 8; ++e) a[e] += (float)v[j][e];
    if (cnt > 8) {
#pragma unroll
        for (int j = 0; j < 8; ++j) {
            int s = __shfl(sidb, 8 + j, 16);
            v[j] = *(const half8*)&H[(size_t)s * DIM + g * 8];
        }
#pragma unroll
        for (int j = 0; j < 8; ++j)
#pragma unroll
            for (int e = 0; e < 8; ++e) a[e] += (float)v[j][e];
        if (cnt > 16) {
            for (int base = 16; base < cnt; base += 16) {
                int m = cnt - base;
                if (m > 16) m = 16;
                int sb = (g < m) ? sl[base + g] : zr;
                for (int j = 0; j < m; ++j) {
                    int s = __shfl(sb, j, 16);
                    half8 vv = *(const half8*)&H[(size_t)s * DIM + g * 8];
#pragma unroll
                    for (int e = 0; e < 8; ++e) a[e] += (float)vv[e];
                }
            }
        }
    }
}

// Scaled gather (hs rows are RAW): per-source dinv = rsqrt(cursor[s]+1) broadcast via shfl.
__device__ __forceinline__ void gather_sum_scaled(
    const _Float16* __restrict__ H, const int* __restrict__ cursor,
    const int* __restrict__ sl, int cnt, int g, int zr, float a[8]) {
    int c16 = cnt < 16 ? cnt : 16;
    int sidb = (g < c16) ? sl[g] : zr;                     // lane g: source g (or zero row)
    float dvb = rsqrtf((float)cursor[sidb] + 1.0f);        // cursor[zr]==0 -> 1.0, v==0
    half8 v[8];
#pragma unroll
    for (int j = 0; j < 8; ++j) {
        int s = __shfl(sidb, j, 16);
        v[j] = *(const half8*)&H[(size_t)s * DIM + g * 8];
    }
#pragma unroll
    for (int j = 0; j < 8; ++j) {
        float sc = __shfl(dvb, j, 16);
#pragma unroll
        for (int e = 0; e < 8; ++e) a[e] = fmaf((float)v[j][e], sc, a[e]);
    }
    if (cnt > 8) {
#pragma unroll
        for (int j = 0; j < 8; ++j) {
            int s = __shfl(sidb, 8 + j, 16);
            v[j] = *(const half8*)&H[(size_t)s * DIM + g * 8];
        }
#pragma unroll
        for (int j = 0; j < 8; ++j) {
            float sc = __shfl(dvb, 8 + j, 16);
#pragma unroll
            for (int e = 0; e < 8; ++e) a[e] = fmaf((float)v[j][e], sc, a[e]);
        }
        if (cnt > 16) {
            for (int base = 16; base < cnt; base += 16) {
                int m = cnt - base;
                if (m > 16) m = 16;
                int sb = (g < m) ? sl[base + g] : zr;
                float db2 = rsqrtf((float)cursor[sb] + 1.0f);
                for (int j = 0; j < m; ++j) {
                    int s = __shfl(sb, j, 16);
                    float sc = __shfl(db2, j, 16);
                    half8 vv = *(const half8*)&H[(size_t)s * DIM + g * 8];
#pragma unroll
                    for (int e = 0; e < 8; ++e) a[e] = fmaf((float)vv[e], sc, a[e]);
                }
            }
        }
    }
}

// ---------------- init: zero cursor (int4) + pack W1/W2 + zero rows n of hs and hs2 ----------------
__global__ __launch_bounds__(256) void k_init(
    int* __restrict__ cursor, int na4, int nzb,
    const float* __restrict__ W1, _Float16* __restrict__ Wp1,
    const float* __restrict__ W2, _Float16* __restrict__ Wp2,
    _Float16* __restrict__ zrow, _Float16* __restrict__ zrow2) {
    int b = blockIdx.x;
    if (b < nzb) {
        int i = b * 256 + threadIdx.x;
        if (i < na4) {
            int4 z = make_int4(0, 0, 0, 0);
            *(int4*)&cursor[i * 4] = z;
        }
        return;
    }
    b -= nzb;
    if (b >= 192) {  // zero rows n of hs and hs2 (gather dead-slot targets)
        if (threadIdx.x < 16) {
            half8 z = 0;
            *(half8*)&zrow[threadIdx.x * 8] = z;
            *(half8*)&zrow2[threadIdx.x * 8] = z;
        }
        return;
    }
    const float* W;
    _Float16* Wp;
    int tid2;
    if (b < 64) { W = W1; Wp = Wp1; tid2 = b * 256 + threadIdx.x; }
    else        { W = W2; Wp = Wp2; tid2 = (b - 64) * 256 + threadIdx.x; }
    // frag (kb,cb): lane l elem j holds W[k=kb*32+(l>>4)*8+j][n=cb*16+(l&15)]
    int jj = tid2 & 7;
    int frag = tid2 >> 3;
    int l = frag & 63;
    int cb = (frag >> 6) & 7;
    int kb = frag >> 9;
    Wp[tid2] = (_Float16)W[(size_t)(kb * 32 + ((l >> 4) << 3) + jj) * DIM + cb * 16 + (l & 15)];
}

// ---------------- front: mm1-raw single GEMM + edge-fill, Bresenham-interleaved ----------------
// Fill blocks: 256 edges (1/thread, short atomic chains). GEMM: hs = f16(x@W1) UNSCALED.
__global__ __launch_bounds__(256, 2) void k_front(
    const float* __restrict__ x, const _Float16* __restrict__ Wp1,
    _Float16* __restrict__ hs, int n, int gb, int total,
    const int* __restrict__ esrc, const int* __restrict__ edst,
    int* __restrict__ cursor, int* __restrict__ srcs, int E) {
    __shared__ _Float16 Hs[64 * 136];
    const int b = blockIdx.x;
    const int gbefore = (int)((long long)b * gb / total);
    const int gafter = (int)(((long long)b + 1) * gb / total);
    if (gafter == gbefore) {
        // ---- edge-fill block (fill index = b - gbefore) ----
        int i = (b - gbefore) * 256 + threadIdx.x;
        if (i < E) {
            int d = edst[i];
            int p = atomicAdd(&cursor[d], 1);
            if (p < CAP) srcs[(size_t)d * CAP + p] = esrc[i];
        }
        return;
    }
    // ---- GEMM block: tile = gbefore ----
    const int tb = gbefore;
    const int tid = threadIdx.x;
    const int w = tid >> 6, l = tid & 63;
    const int row0 = tb * 64;
    const int arow = row0 + w * 16 + (l & 15);
    const int kq = (l >> 4) << 3;
    const bool ok = arow < n;
    const float* xr = &x[(size_t)arow * DIM + kq];

    f32x4 ah[8];
#pragma unroll
    for (int cb = 0; cb < 8; ++cb) {
        f32x4 z = {0.f, 0.f, 0.f, 0.f};
        ah[cb] = z;
    }

#pragma unroll
    for (int kb = 0; kb < 4; ++kb) {
        float4 v0 = make_float4(0.f, 0.f, 0.f, 0.f), v1 = v0;
        if (ok) {
            v0 = *(const float4*)&xr[kb * 32];
            v1 = *(const float4*)&xr[kb * 32 + 4];
        }
        half8 a;
        a[0] = (_Float16)v0.x; a[1] = (_Float16)v0.y;
        a[2] = (_Float16)v0.z; a[3] = (_Float16)v0.w;
        a[4] = (_Float16)v1.x; a[5] = (_Float16)v1.y;
        a[6] = (_Float16)v1.z; a[7] = (_Float16)v1.w;
#pragma unroll
        for (int cb = 0; cb < 8; ++cb) {
            half8 bf = *(const half8*)&Wp1[((kb * 8 + cb) * 64 + l) * 8];
            ah[cb] = __builtin_amdgcn_mfma_f32_16x16x32_f16(a, bf, ah[cb], 0, 0, 0);
        }
    }
    // hs RAW: accs -> LDS -> coalesced stores (no dinv here; applied in mm2g gather)
    const int orow = w * 16 + ((l >> 4) << 2);
    const int oc = l & 15;
#pragma unroll
    for (int reg = 0; reg < 4; ++reg) {
#pragma unroll
        for (int cb = 0; cb < 8; ++cb)
            Hs[(orow + reg) * 136 + cb * 16 + oc] = (_Float16)ah[cb][reg];
    }
    __syncthreads();
#pragma unroll
    for (int it = 0; it < 4; ++it) {
        int i = it * 256 + tid;          // 1024 chunks of 8 halfs
        int r = i >> 4, c = (i & 15) * 8;
        if (row0 + r < n)
            *(half8*)&hs[(size_t)(row0 + r) * DIM + c] = *(const half8*)&Hs[r * 136 + c];
    }
}

// ---------------- mm2g: gather1 (scaled) + full GEMM2; x loads+cvt hoisted ----------------
__global__ __launch_bounds__(256, 2) void k_mm2g(
    const float* __restrict__ x, const _Float16* __restrict__ hs,
    const int* __restrict__ cursor, const int* __restrict__ srcs,
    const float* __restrict__ b1, const _Float16* __restrict__ Wp2,
    _Float16* __restrict__ hs2, int n) {
    __shared__ _Float16 LS[64 * 136];  // Af = first 8192 halfs; reused as Hs after MFMA
    const int tid = threadIdx.x;
    const int w = tid >> 6, l = tid & 63;
    const int g = tid & 15, gid = tid >> 4;
    const int row0 = blockIdx.x * 64;

    // ---- x streaming loads + f16/lrelu cvt, issued up-front (retire under gather) ----
    const int arow = row0 + w * 16 + (l & 15);
    const int kq = (l >> 4) << 3;
    const bool ok = arow < n;
    const float* xr = &x[(size_t)arow * DIM + kq];
    half8 al[4];
#pragma unroll
    for (int kb = 0; kb < 4; ++kb) {
        float4 v0 = make_float4(0.f, 0.f, 0.f, 0.f), v1 = v0;
        if (ok) {
            v0 = *(const float4*)&xr[kb * 32];
            v1 = *(const float4*)&xr[kb * 32 + 4];
        }
        half8 a;
        a[0] = (_Float16)v0.x; a[1] = (_Float16)v0.y;
        a[2] = (_Float16)v0.z; a[3] = (_Float16)v0.w;
        a[4] = (_Float16)v1.x; a[5] = (_Float16)v1.y;
        a[6] = (_Float16)v1.z; a[7] = (_Float16)v1.w;
#pragma unroll
        for (int e = 0; e < 8; ++e) {
            _Float16 t = a[e];
            al[kb][e] = (t > (_Float16)0.f) ? t : t * (_Float16)0.01f;
        }
    }

    f32x4 acc[8];
#pragma unroll
    for (int cb = 0; cb < 8; ++cb) {
        f32x4 z = {0.f, 0.f, 0.f, 0.f};
        acc[cb] = z;
    }

    // gather: 16 lanes per node, hs rows raw -> per-source dinv applied in-loop
#pragma unroll
    for (int it = 0; it < 4; ++it) {
        int node = row0 + it * 16 + gid;
        half8 o = 0;
        if (node < n) {
            int rawc = cursor[node];
            int cnt = rawc > CAP ? CAP : rawc;
            const int* sl = &srcs[(size_t)node * CAP];
            float d = rsqrtf((float)rawc + 1.0f);
            half8 h = *(const half8*)&hs[(size_t)node * DIM + g * 8];
            float a[8];
#pragma unroll
            for (int e = 0; e < 8; ++e) a[e] = (float)h[e] * d;   // self term: h*dinv(node)
            gather_sum_scaled(hs, cursor, sl, cnt, g, n, a);
            const float4 bb0 = *(const float4*)&b1[g * 8];
            const float4 bb1 = *(const float4*)&b1[g * 8 + 4];
            o[0] = (_Float16)lrelu(fmaf(a[0], d, bb0.x));
            o[1] = (_Float16)lrelu(fmaf(a[1], d, bb0.y));
            o[2] = (_Float16)lrelu(fmaf(a[2], d, bb0.z));
            o[3] = (_Float16)lrelu(fmaf(a[3], d, bb0.w));
            o[4] = (_Float16)lrelu(fmaf(a[4], d, bb1.x));
            o[5] = (_Float16)lrelu(fmaf(a[5], d, bb1.y));
            o[6] = (_Float16)lrelu(fmaf(a[6], d, bb1.z));
            o[7] = (_Float16)lrelu(fmaf(a[7], d, bb1.w));
        }
        // A-frag write: frag = it*4 + (g>>2); lane-in-frag = (g&3)*16 + gid  (row m = gid)
        *(half8*)&LS[(((it * 4 + (g >> 2)) * 64) + (g & 3) * 16 + gid) * 8] = o;
    }

    // x-half GEMM: acc += lrelu(f16(x_tile)) @ W2[0:128,:]
#pragma unroll
    for (int kb = 0; kb < 4; ++kb) {
#pragma unroll
        for (int cb = 0; cb < 8; ++cb) {
            half8 bf = *(const half8*)&Wp2[((kb * 8 + cb) * 64 + l) * 8];  // W2 rows 0..127
            acc[cb] = __builtin_amdgcn_mfma_f32_16x16x32_f16(al[kb], bf, acc[cb], 0, 0, 0);
        }
    }
    __syncthreads();

#pragma unroll
    for (int kb = 0; kb < 4; ++kb) {
        half8 a = *(const half8*)&LS[((w * 4 + kb) * 64 + l) * 8];
#pragma unroll
        for (int cb = 0; cb < 8; ++cb) {
            half8 bf = *(const half8*)&Wp2[(((kb + 4) * 8 + cb) * 64 + l) * 8];  // W2 rows 128..255
            acc[cb] = __builtin_amdgcn_mfma_f32_16x16x32_f16(a, bf, acc[cb], 0, 0, 0);
        }
    }
    __syncthreads();  // all waves done reading Af before Hs overwrite
    const int orow = w * 16 + ((l >> 4) << 2);
    const int oc = l & 15;
#pragma unroll
    for (int reg = 0; reg < 4; ++reg) {
        int grow = row0 + orow + reg;
        float d = (grow < n) ? rsqrtf((float)cursor[grow] + 1.0f) : 0.f;
#pragma unroll
        for (int cb = 0; cb < 8; ++cb)
            LS[(orow + reg) * 136 + cb * 16 + oc] = (_Float16)(acc[cb][reg] * d);
    }
    __syncthreads();
#pragma unroll
    for (int it = 0; it < 4; ++it) {
        int i = it * 256 + tid;
        int r = i >> 4, c = (i & 15) * 8;
        if (row0 + r < n)
            *(half8*)&hs2[(size_t)(row0 + r) * DIM + c] = *(const half8*)&LS[r * 136 + c];
    }
}

// ---------------- gather2 + final projection (16-lane groups; hs2 pre-scaled) ----------------
__global__ __launch_bounds__(256) void k_gather2(
    const _Float16* __restrict__ hs2, const int* __restrict__ cursor,
    const int* __restrict__ srcs, const float* __restrict__ b2,
    const float* __restrict__ wout, const float* __restrict__ bout,
    float* __restrict__ out, int n) {
    const int node = blockIdx.x * 16 + (threadIdx.x >> 4);
    const int g = threadIdx.x & 15;
    if (node >= n) return;
    int rawc = cursor[node];
    int cnt = rawc > CAP ? CAP : rawc;
    const int* sl = &srcs[(size_t)node * CAP];
    half8 h = *(const half8*)&hs2[(size_t)node * DIM + g * 8];
    float a[8];
#pragma unroll
    for (int e = 0; e < 8; ++e) a[e] = (float)h[e];
    gather_sum(hs2, sl, cnt, g, n, a);
    float d = rsqrtf((float)rawc + 1.0f);
    const float4 bb0 = *(const float4*)&b2[g * 8];
    const float4 bb1 = *(const float4*)&b2[g * 8 + 4];
    const float4 wv0 = *(const float4*)&wout[g * 8];
    const float4 wv1 = *(const float4*)&wout[g * 8 + 4];
    float s = lrelu(fmaf(a[0], d, bb0.x)) * wv0.x + lrelu(fmaf(a[1], d, bb0.y)) * wv0.y +
              lrelu(fmaf(a[2], d, bb0.z)) * wv0.z + lrelu(fmaf(a[3], d, bb0.w)) * wv0.w +
              lrelu(fmaf(a[4], d, bb1.x)) * wv1.x + lrelu(fmaf(a[5], d, bb1.y)) * wv1.y +
              lrelu(fmaf(a[6], d, bb1.z)) * wv1.z + lrelu(fmaf(a[7], d, bb1.w)) * wv1.w;
#pragma unroll
    for (int off = 8; off > 0; off >>= 1) s += __shfl_down(s, off, 16);
    if (g == 0) out[node] = s + bout[0];
}

extern "C" void kernel_launch(void* const* d_in, const int* in_sizes, int n_in,
                              void* d_out, int out_size, void* d_ws, size_t ws_size,
                              hipStream_t stream) {
    const float* x    = (const float*)d_in[0];
    const int*   ei   = (const int*)d_in[1];
    const float* W1   = (const float*)d_in[2];
    const float* b1   = (const float*)d_in[3];
    const float* W2   = (const float*)d_in[4];
    const float* b2   = (const float*)d_in[5];
    const float* Wout = (const float*)d_in[6];
    const float* bout = (const float*)d_in[7];
    float* out = (float*)d_out;

    const int N = in_sizes[0] / DIM;
    const int E = in_sizes[1] / 2;
    const int* src = ei;      // edge_index[0]
    const int* dst = ei + E;  // edge_index[1]

    const int gb = (N + 63) / 64;
    const long long nx = (long long)N * DIM;

    // workspace
    size_t Na = ((size_t)N + 63) & ~(size_t)63;   // covers index N (zero-row degree)
    int* cursor   = (int*)d_ws;                            // Na
    int* srcs     = cursor + Na;                           // (N+1)*CAP (row N spare)
    _Float16* Wp1 = (_Float16*)(srcs + ((size_t)N + 1) * CAP); // 128*128
    _Float16* Wp2 = Wp1 + 128 * 128;                       // 256*128
    _Float16* hsb = Wp2 + 256 * 128;                       // (N+1)*128 (hs + zero row n)
    _Float16* hs2 = hsb + nx + DIM;                        // (N+1)*128 (hs2 + zero row n)

    const int eb = (E + 255) / 256;
    const int total = gb + eb;
    const int na4 = (int)(Na / 4);
    const int nzb = (na4 + 255) / 256;

    k_init<<<nzb + 193, 256, 0, stream>>>(cursor, na4, nzb, W1, Wp1, W2, Wp2,
                                          hsb + nx, hs2 + nx);
    k_front<<<total, 256, 0, stream>>>(x, Wp1, hsb, N, gb, total, src, dst, cursor, srcs, E);
    k_mm2g<<<gb, 256, 0, stream>>>(x, hsb, cursor, srcs, b1, Wp2, hs2, N);
    k_gather2<<<(N + 15) / 16, 256, 0, stream>>>(hs2, cursor, srcs, b2, Wout, bout, out, N);
}

// Round 9
// 231.077 us; speedup vs baseline: 1.0378x; 1.0378x over previous
//
#include <hip/hip_runtime.h>

#define DIM 128
#define CAP 48

typedef _Float16 half8 __attribute__((ext_vector_type(8)));
typedef float f32x4 __attribute__((ext_vector_type(4)));

__device__ __forceinline__ float lrelu(float v) { return v > 0.f ? v : 0.01f * v; }

// Unscaled gather (hs2 rows are pre-scaled): 8-wide bursts, dead slots -> zero row zr.
__device__ __forceinline__ void gather_sum(
    const _Float16* __restrict__ H, const int* __restrict__ sl,
    int cnt, int g, int zr, float a[8]) {
    int c16 = cnt < 16 ? cnt : 16;
    int sidb = (g < c16) ? sl[g] : zr;
    half8 v[8];
#pragma unroll
    for (int j = 0; j < 8; ++j) {
        int s = __shfl(sidb, j, 16);
        v[j] = *(const half8*)&H[(size_t)s * DIM + g * 8];
    }
#pragma unroll
    for (int j = 0; j < 8; ++j)
#pragma unroll
        for (int e = 0; e < 8; ++e) a[e] += (float)v[j][e];
    if (cnt > 8) {
#pragma unroll
        for (int j = 0; j < 8; ++j) {
            int s = __shfl(sidb, 8 + j, 16);
            v[j] = *(const half8*)&H[(size_t)s * DIM + g * 8];
        }
#pragma unroll
        for (int j = 0; j < 8; ++j)
#pragma unroll
            for (int e = 0; e < 8; ++e) a[e] += (float)v[j][e];
        if (cnt > 16) {
            for (int base = 16; base < cnt; base += 16) {
                int m = cnt - base;
                if (m > 16) m = 16;
                int sb = (g < m) ? sl[base + g] : zr;
                for (int j = 0; j < m; ++j) {
                    int s = __shfl(sb, j, 16);
                    half8 vv = *(const half8*)&H[(size_t)s * DIM + g * 8];
#pragma unroll
                    for (int e = 0; e < 8; ++e) a[e] += (float)vv[e];
                }
            }
        }
    }
}

// Scaled gather (hs rows are RAW): per-source dinv = rsqrt(cursor[s]+1) broadcast via shfl.
__device__ __forceinline__ void gather_sum_scaled(
    const _Float16* __restrict__ H, const int* __restrict__ cursor,
    const int* __restrict__ sl, int cnt, int g, int zr, float a[8]) {
    int c16 = cnt < 16 ? cnt : 16;
    int sidb = (g < c16) ? sl[g] : zr;                     // lane g: source g (or zero row)
    float dvb = rsqrtf((float)cursor[sidb] + 1.0f);        // cursor[zr]==0 -> 1.0, v==0
    half8 v[8];
#pragma unroll
    for (int j = 0; j < 8; ++j) {
        int s = __shfl(sidb, j, 16);
        v[j] = *(const half8*)&H[(size_t)s * DIM + g * 8];
    }
#pragma unroll
    for (int j = 0; j < 8; ++j) {
        float sc = __shfl(dvb, j, 16);
#pragma unroll
        for (int e = 0; e < 8; ++e) a[e] = fmaf((float)v[j][e], sc, a[e]);
    }
    if (cnt > 8) {
#pragma unroll
        for (int j = 0; j < 8; ++j) {
            int s = __shfl(sidb, 8 + j, 16);
            v[j] = *(const half8*)&H[(size_t)s * DIM + g * 8];
        }
#pragma unroll
        for (int j = 0; j < 8; ++j) {
            float sc = __shfl(dvb, 8 + j, 16);
#pragma unroll
            for (int e = 0; e < 8; ++e) a[e] = fmaf((float)v[j][e], sc, a[e]);
        }
        if (cnt > 16) {
            for (int base = 16; base < cnt; base += 16) {
                int m = cnt - base;
                if (m > 16) m = 16;
                int sb = (g < m) ? sl[base + g] : zr;
                float db2 = rsqrtf((float)cursor[sb] + 1.0f);
                for (int j = 0; j < m; ++j) {
                    int s = __shfl(sb, j, 16);
                    float sc = __shfl(db2, j, 16);
                    half8 vv = *(const half8*)&H[(size_t)s * DIM + g * 8];
#pragma unroll
                    for (int e = 0; e < 8; ++e) a[e] = fmaf((float)vv[e], sc, a[e]);
                }
            }
        }
    }
}

// ---------------- init: zero cursor (int4) + pack W1/W2 + zero rows n of hs and hs2 ----------------
__global__ __launch_bounds__(256) void k_init(
    int* __restrict__ cursor, int na4, int nzb,
    const float* __restrict__ W1, _Float16* __restrict__ Wp1,
    const float* __restrict__ W2, _Float16* __restrict__ Wp2,
    _Float16* __restrict__ zrow, _Float16* __restrict__ zrow2) {
    int b = blockIdx.x;
    if (b < nzb) {
        int i = b * 256 + threadIdx.x;
        if (i < na4) {
            int4 z = make_int4(0, 0, 0, 0);
            *(int4*)&cursor[i * 4] = z;
        }
        return;
    }
    b -= nzb;
    if (b >= 192) {  // zero rows n of hs and hs2 (gather dead-slot targets)
        if (threadIdx.x < 16) {
            half8 z = 0;
            *(half8*)&zrow[threadIdx.x * 8] = z;
            *(half8*)&zrow2[threadIdx.x * 8] = z;
        }
        return;
    }
    const float* W;
    _Float16* Wp;
    int tid2;
    if (b < 64) { W = W1; Wp = Wp1; tid2 = b * 256 + threadIdx.x; }
    else        { W = W2; Wp = Wp2; tid2 = (b - 64) * 256 + threadIdx.x; }
    // frag (kb,cb): lane l elem j holds W[k=kb*32+(l>>4)*8+j][n=cb*16+(l&15)]
    int jj = tid2 & 7;
    int frag = tid2 >> 3;
    int l = frag & 63;
    int cb = (frag >> 6) & 7;
    int kb = frag >> 9;
    Wp[tid2] = (_Float16)W[(size_t)(kb * 32 + ((l >> 4) << 3) + jj) * DIM + cb * 16 + (l & 15)];
}

// ---------------- front: mm1-raw single GEMM (hs = f16(x@W1), UNSCALED) + edge-fill tail ----------------
// blocks [0,gb): GEMM; blocks [gb,gb+eb): edge fill (atomic cursor + srcs scatter).
__global__ __launch_bounds__(256, 2) void k_front(
    const float* __restrict__ x, const _Float16* __restrict__ Wp1,
    _Float16* __restrict__ hs, int n, int gb,
    const int* __restrict__ esrc, const int* __restrict__ edst,
    int* __restrict__ cursor, int* __restrict__ srcs, int E) {
    __shared__ _Float16 Hs[64 * 136];
    const int bb = blockIdx.x;
    if (bb >= gb) {
        int i = (bb - gb) * 256 + threadIdx.x;
        if (i < E) {
            int d = edst[i];
            int p = atomicAdd(&cursor[d], 1);
            if (p < CAP) srcs[(size_t)d * CAP + p] = esrc[i];
        }
        return;
    }
    const int tid = threadIdx.x;
    const int w = tid >> 6, l = tid & 63;
    const int row0 = bb * 64;
    const int arow = row0 + w * 16 + (l & 15);
    const int kq = (l >> 4) << 3;
    const bool ok = arow < n;
    const float* xr = &x[(size_t)arow * DIM + kq];

    f32x4 ah[8];
#pragma unroll
    for (int cb = 0; cb < 8; ++cb) {
        f32x4 z = {0.f, 0.f, 0.f, 0.f};
        ah[cb] = z;
    }

#pragma unroll
    for (int kb = 0; kb < 4; ++kb) {
        float4 v0 = make_float4(0.f, 0.f, 0.f, 0.f), v1 = v0;
        if (ok) {
            v0 = *(const float4*)&xr[kb * 32];
            v1 = *(const float4*)&xr[kb * 32 + 4];
        }
        half8 a;
        a[0] = (_Float16)v0.x; a[1] = (_Float16)v0.y;
        a[2] = (_Float16)v0.z; a[3] = (_Float16)v0.w;
        a[4] = (_Float16)v1.x; a[5] = (_Float16)v1.y;
        a[6] = (_Float16)v1.z; a[7] = (_Float16)v1.w;
#pragma unroll
        for (int cb = 0; cb < 8; ++cb) {
            half8 bf = *(const half8*)&Wp1[((kb * 8 + cb) * 64 + l) * 8];
            ah[cb] = __builtin_amdgcn_mfma_f32_16x16x32_f16(a, bf, ah[cb], 0, 0, 0);
        }
    }
    // hs RAW: accs -> LDS -> coalesced stores (no dinv here; applied in mm2g gather)
    const int orow = w * 16 + ((l >> 4) << 2);
    const int oc = l & 15;
#pragma unroll
    for (int reg = 0; reg < 4; ++reg) {
#pragma unroll
        for (int cb = 0; cb < 8; ++cb)
            Hs[(orow + reg) * 136 + cb * 16 + oc] = (_Float16)ah[cb][reg];
    }
    __syncthreads();
#pragma unroll
    for (int it = 0; it < 4; ++it) {
        int i = it * 256 + tid;          // 1024 chunks of 8 halfs
        int r = i >> 4, c = (i & 15) * 8;
        if (row0 + r < n)
            *(half8*)&hs[(size_t)(row0 + r) * DIM + c] = *(const half8*)&Hs[r * 136 + c];
    }
}

// ---------------- mm2g: gather1 (scaled) + full GEMM2 (x-half computed in-kernel) ----------------
// acc = lrelu(f16(x))@W2[0:128] (streaming GEMM, overlaps gather stalls) + gathered-y@W2[128:256]
__global__ __launch_bounds__(256, 2) void k_mm2g(
    const float* __restrict__ x, const _Float16* __restrict__ hs,
    const int* __restrict__ cursor, const int* __restrict__ srcs,
    const float* __restrict__ b1, const _Float16* __restrict__ Wp2,
    _Float16* __restrict__ hs2, int n) {
    __shared__ _Float16 LS[64 * 136];  // Af = first 8192 halfs; reused as Hs after MFMA
    const int tid = threadIdx.x;
    const int w = tid >> 6, l = tid & 63;
    const int g = tid & 15, gid = tid >> 4;
    const int row0 = blockIdx.x * 64;

    f32x4 acc[8];
#pragma unroll
    for (int cb = 0; cb < 8; ++cb) {
        f32x4 z = {0.f, 0.f, 0.f, 0.f};
        acc[cb] = z;
    }

    // gather: 16 lanes per node, hs rows raw -> per-source dinv applied in-loop
#pragma unroll
    for (int it = 0; it < 4; ++it) {
        int node = row0 + it * 16 + gid;
        half8 o = 0;
        if (node < n) {
            int rawc = cursor[node];
            int cnt = rawc > CAP ? CAP : rawc;
            const int* sl = &srcs[(size_t)node * CAP];
            float d = rsqrtf((float)rawc + 1.0f);
            half8 h = *(const half8*)&hs[(size_t)node * DIM + g * 8];
            float a[8];
#pragma unroll
            for (int e = 0; e < 8; ++e) a[e] = (float)h[e] * d;   // self term: h*dinv(node)
            gather_sum_scaled(hs, cursor, sl, cnt, g, n, a);
            const float4 bb0 = *(const float4*)&b1[g * 8];
            const float4 bb1 = *(const float4*)&b1[g * 8 + 4];
            o[0] = (_Float16)lrelu(fmaf(a[0], d, bb0.x));
            o[1] = (_Float16)lrelu(fmaf(a[1], d, bb0.y));
            o[2] = (_Float16)lrelu(fmaf(a[2], d, bb0.z));
            o[3] = (_Float16)lrelu(fmaf(a[3], d, bb0.w));
            o[4] = (_Float16)lrelu(fmaf(a[4], d, bb1.x));
            o[5] = (_Float16)lrelu(fmaf(a[5], d, bb1.y));
            o[6] = (_Float16)lrelu(fmaf(a[6], d, bb1.z));
            o[7] = (_Float16)lrelu(fmaf(a[7], d, bb1.w));
        }
        // A-frag write: frag = it*4 + (g>>2); lane-in-frag = (g&3)*16 + gid  (row m = gid)
        *(half8*)&LS[(((it * 4 + (g >> 2)) * 64) + (g & 3) * 16 + gid) * 8] = o;
    }

    // x-half GEMM: acc += lrelu(f16(x_tile)) @ W2[0:128,:]  (same math as old P, minus f16 round-trip)
    {
        const int arow = row0 + w * 16 + (l & 15);
        const int kq = (l >> 4) << 3;
        const bool ok = arow < n;
        const float* xr = &x[(size_t)arow * DIM + kq];
#pragma unroll
        for (int kb = 0; kb < 4; ++kb) {
            float4 v0 = make_float4(0.f, 0.f, 0.f, 0.f), v1 = v0;
            if (ok) {
                v0 = *(const float4*)&xr[kb * 32];
                v1 = *(const float4*)&xr[kb * 32 + 4];
            }
            half8 a, al;
            a[0] = (_Float16)v0.x; a[1] = (_Float16)v0.y;
            a[2] = (_Float16)v0.z; a[3] = (_Float16)v0.w;
            a[4] = (_Float16)v1.x; a[5] = (_Float16)v1.y;
            a[6] = (_Float16)v1.z; a[7] = (_Float16)v1.w;
#pragma unroll
            for (int e = 0; e < 8; ++e) {
                _Float16 t = a[e];
                al[e] = (t > (_Float16)0.f) ? t : t * (_Float16)0.01f;
            }
#pragma unroll
            for (int cb = 0; cb < 8; ++cb) {
                half8 bf = *(const half8*)&Wp2[((kb * 8 + cb) * 64 + l) * 8];  // W2 rows 0..127
                acc[cb] = __builtin_amdgcn_mfma_f32_16x16x32_f16(al, bf, acc[cb], 0, 0, 0);
            }
        }
    }
    __syncthreads();

#pragma unroll
    for (int kb = 0; kb < 4; ++kb) {
        half8 a = *(const half8*)&LS[((w * 4 + kb) * 64 + l) * 8];
#pragma unroll
        for (int cb = 0; cb < 8; ++cb) {
            half8 bf = *(const half8*)&Wp2[(((kb + 4) * 8 + cb) * 64 + l) * 8];  // W2 rows 128..255
            acc[cb] = __builtin_amdgcn_mfma_f32_16x16x32_f16(a, bf, acc[cb], 0, 0, 0);
        }
    }
    __syncthreads();  // all waves done reading Af before Hs overwrite
    const int orow = w * 16 + ((l >> 4) << 2);
    const int oc = l & 15;
#pragma unroll
    for (int reg = 0; reg < 4; ++reg) {
        int grow = row0 + orow + reg;
        float d = (grow < n) ? rsqrtf((float)cursor[grow] + 1.0f) : 0.f;
#pragma unroll
        for (int cb = 0; cb < 8; ++cb)
            LS[(orow + reg) * 136 + cb * 16 + oc] = (_Float16)(acc[cb][reg] * d);
    }
    __syncthreads();
#pragma unroll
    for (int it = 0; it < 4; ++it) {
        int i = it * 256 + tid;
        int r = i >> 4, c = (i & 15) * 8;
        if (row0 + r < n)
            *(half8*)&hs2[(size_t)(row0 + r) * DIM + c] = *(const half8*)&LS[r * 136 + c];
    }
}

// ---------------- gather2 + final projection (16-lane groups; hs2 pre-scaled) ----------------
__global__ __launch_bounds__(256) void k_gather2(
    const _Float16* __restrict__ hs2, const int* __restrict__ cursor,
    const int* __restrict__ srcs, const float* __restrict__ b2,
    const float* __restrict__ wout, const float* __restrict__ bout,
    float* __restrict__ out, int n) {
    const int node = blockIdx.x * 16 + (threadIdx.x >> 4);
    const int g = threadIdx.x & 15;
    if (node >= n) return;
    int rawc = cursor[node];
    int cnt = rawc > CAP ? CAP : rawc;
    const int* sl = &srcs[(size_t)node * CAP];
    half8 h = *(const half8*)&hs2[(size_t)node * DIM + g * 8];
    float a[8];
#pragma unroll
    for (int e = 0; e < 8; ++e) a[e] = (float)h[e];
    gather_sum(hs2, sl, cnt, g, n, a);
    float d = rsqrtf((float)rawc + 1.0f);
    const float4 bb0 = *(const float4*)&b2[g * 8];
    const float4 bb1 = *(const float4*)&b2[g * 8 + 4];
    const float4 wv0 = *(const float4*)&wout[g * 8];
    const float4 wv1 = *(const float4*)&wout[g * 8 + 4];
    float s = lrelu(fmaf(a[0], d, bb0.x)) * wv0.x + lrelu(fmaf(a[1], d, bb0.y)) * wv0.y +
              lrelu(fmaf(a[2], d, bb0.z)) * wv0.z + lrelu(fmaf(a[3], d, bb0.w)) * wv0.w +
              lrelu(fmaf(a[4], d, bb1.x)) * wv1.x + lrelu(fmaf(a[5], d, bb1.y)) * wv1.y +
              lrelu(fmaf(a[6], d, bb1.z)) * wv1.z + lrelu(fmaf(a[7], d, bb1.w)) * wv1.w;
#pragma unroll
    for (int off = 8; off > 0; off >>= 1) s += __shfl_down(s, off, 16);
    if (g == 0) out[node] = s + bout[0];
}

extern "C" void kernel_launch(void* const* d_in, const int* in_sizes, int n_in,
                              void* d_out, int out_size, void* d_ws, size_t ws_size,
                              hipStream_t stream) {
    const float* x    = (const float*)d_in[0];
    const int*   ei   = (const int*)d_in[1];
    const float* W1   = (const float*)d_in[2];
    const float* b1   = (const float*)d_in[3];
    const float* W2   = (const float*)d_in[4];
    const float* b2   = (const float*)d_in[5];
    const float* Wout = (const float*)d_in[6];
    const float* bout = (const float*)d_in[7];
    float* out = (float*)d_out;

    const int N = in_sizes[0] / DIM;
    const int E = in_sizes[1] / 2;
    const int* src = ei;      // edge_index[0]
    const int* dst = ei + E;  // edge_index[1]

    const int gb = (N + 63) / 64;
    const long long nx = (long long)N * DIM;

    // workspace
    size_t Na = ((size_t)N + 63) & ~(size_t)63;   // covers index N (zero-row degree)
    int* cursor   = (int*)d_ws;                            // Na
    int* srcs     = cursor + Na;                           // (N+1)*CAP (row N = clamp target)
    _Float16* Wp1 = (_Float16*)(srcs + ((size_t)N + 1) * CAP); // 128*128
    _Float16* Wp2 = Wp1 + 128 * 128;                       // 256*128
    _Float16* hsb = Wp2 + 256 * 128;                       // (N+1)*128 (hs + zero row n)
    _Float16* hs2 = hsb + nx + DIM;                        // (N+1)*128 (hs2 + zero row n)

    const int eb = (E + 255) / 256;
    const int na4 = (int)(Na / 4);
    const int nzb = (na4 + 255) / 256;

    k_init<<<nzb + 193, 256, 0, stream>>>(cursor, na4, nzb, W1, Wp1, W2, Wp2,
                                          hsb + nx, hs2 + nx);
    k_front<<<gb + eb, 256, 0, stream>>>(x, Wp1, hsb, N, gb, src, dst, cursor, srcs, E);
    k_mm2g<<<gb, 256, 0, stream>>>(x, hsb, cursor, srcs, b1, Wp2, hs2, N);
    k_gather2<<<(N + 15) / 16, 256, 0, stream>>>(hs2, cursor, srcs, b2, Wout, bout, out, N);
}

// Round 10
// 208.400 us; speedup vs baseline: 1.1507x; 1.1088x over previous
//
#include <hip/hip_runtime.h>

#define DIM 128
#define CAP 48

typedef _Float16 half8 __attribute__((ext_vector_type(8)));
typedef float f32x4 __attribute__((ext_vector_type(4)));

__device__ __forceinline__ float lrelu(float v) { return v > 0.f ? v : 0.01f * v; }

// Unscaled gather (hs2 rows are pre-scaled): 8-wide bursts, dead slots -> zero row zr.
__device__ __forceinline__ void gather_sum(
    const _Float16* __restrict__ H, const int* __restrict__ sl,
    int cnt, int g, int zr, float a[8]) {
    int c16 = cnt < 16 ? cnt : 16;
    int sidb = (g < c16) ? sl[g] : zr;
    half8 v[8];
#pragma unroll
    for (int j = 0; j < 8; ++j) {
        int s = __shfl(sidb, j, 16);
        v[j] = *(const half8*)&H[(size_t)s * DIM + g * 8];
    }
#pragma unroll
    for (int j = 0; j < 8; ++j)
#pragma unroll
        for (int e = 0; e < 8; ++e) a[e] += (float)v[j][e];
    if (cnt > 8) {
#pragma unroll
        for (int j = 0; j < 8; ++j) {
            int s = __shfl(sidb, 8 + j, 16);
            v[j] = *(const half8*)&H[(size_t)s * DIM + g * 8];
        }
#pragma unroll
        for (int j = 0; j < 8; ++j)
#pragma unroll
            for (int e = 0; e < 8; ++e) a[e] += (float)v[j][e];
        if (cnt > 16) {
            for (int base = 16; base < cnt; base += 16) {
                int m = cnt - base;
                if (m > 16) m = 16;
                int sb = (g < m) ? sl[base + g] : zr;
                for (int j = 0; j < m; ++j) {
                    int s = __shfl(sb, j, 16);
                    half8 vv = *(const half8*)&H[(size_t)s * DIM + g * 8];
#pragma unroll
                    for (int e = 0; e < 8; ++e) a[e] += (float)vv[e];
                }
            }
        }
    }
}

// Scaled gather (hs rows are RAW): per-source dinv = rsqrt(cursor[s]+1) broadcast via shfl.
__device__ __forceinline__ void gather_sum_scaled(
    const _Float16* __restrict__ H, const int* __restrict__ cursor,
    const int* __restrict__ sl, int cnt, int g, int zr, float a[8]) {
    int c16 = cnt < 16 ? cnt : 16;
    int sidb = (g < c16) ? sl[g] : zr;                     // lane g: source g (or zero row)
    float dvb = rsqrtf((float)cursor[sidb] + 1.0f);        // cursor[zr]==0 -> 1.0, v==0
    half8 v[8];
#pragma unroll
    for (int j = 0; j < 8; ++j) {
        int s = __shfl(sidb, j, 16);
        v[j] = *(const half8*)&H[(size_t)s * DIM + g * 8];
    }
#pragma unroll
    for (int j = 0; j < 8; ++j) {
        float sc = __shfl(dvb, j, 16);
#pragma unroll
        for (int e = 0; e < 8; ++e) a[e] = fmaf((float)v[j][e], sc, a[e]);
    }
    if (cnt > 8) {
#pragma unroll
        for (int j = 0; j < 8; ++j) {
            int s = __shfl(sidb, 8 + j, 16);
            v[j] = *(const half8*)&H[(size_t)s * DIM + g * 8];
        }
#pragma unroll
        for (int j = 0; j < 8; ++j) {
            float sc = __shfl(dvb, 8 + j, 16);
#pragma unroll
            for (int e = 0; e < 8; ++e) a[e] = fmaf((float)v[j][e], sc, a[e]);
        }
        if (cnt > 16) {
            for (int base = 16; base < cnt; base += 16) {
                int m = cnt - base;
                if (m > 16) m = 16;
                int sb = (g < m) ? sl[base + g] : zr;
                float db2 = rsqrtf((float)cursor[sb] + 1.0f);
                for (int j = 0; j < m; ++j) {
                    int s = __shfl(sb, j, 16);
                    float sc = __shfl(db2, j, 16);
                    half8 vv = *(const half8*)&H[(size_t)s * DIM + g * 8];
#pragma unroll
                    for (int e = 0; e < 8; ++e) a[e] = fmaf((float)vv[e], sc, a[e]);
                }
            }
        }
    }
}

// ---------------- init: zero cursor (int4) + pack W1/W2 + zero rows n of hs and hs2 ----------------
__global__ __launch_bounds__(256) void k_init(
    int* __restrict__ cursor, int na4, int nzb,
    const float* __restrict__ W1, _Float16* __restrict__ Wp1,
    const float* __restrict__ W2, _Float16* __restrict__ Wp2,
    _Float16* __restrict__ zrow, _Float16* __restrict__ zrow2) {
    int b = blockIdx.x;
    if (b < nzb) {
        int i = b * 256 + threadIdx.x;
        if (i < na4) {
            int4 z = make_int4(0, 0, 0, 0);
            *(int4*)&cursor[i * 4] = z;
        }
        return;
    }
    b -= nzb;
    if (b >= 192) {  // zero rows n of hs and hs2 (gather dead-slot targets)
        if (threadIdx.x < 16) {
            half8 z = 0;
            *(half8*)&zrow[threadIdx.x * 8] = z;
            *(half8*)&zrow2[threadIdx.x * 8] = z;
        }
        return;
    }
    const float* W;
    _Float16* Wp;
    int tid2;
    if (b < 64) { W = W1; Wp = Wp1; tid2 = b * 256 + threadIdx.x; }
    else        { W = W2; Wp = Wp2; tid2 = (b - 64) * 256 + threadIdx.x; }
    // frag (kb,cb): lane l elem j holds W[k=kb*32+(l>>4)*8+j][n=cb*16+(l&15)]
    int jj = tid2 & 7;
    int frag = tid2 >> 3;
    int l = frag & 63;
    int cb = (frag >> 6) & 7;
    int kb = frag >> 9;
    Wp[tid2] = (_Float16)W[(size_t)(kb * 32 + ((l >> 4) << 3) + jj) * DIM + cb * 16 + (l & 15)];
}

// ---------------- front: mm1-raw single GEMM (hs = f16(x@W1), UNSCALED) + edge-fill tail ----------------
// blocks [0,gb): GEMM; blocks [gb,gb+eb): edge fill (atomic cursor + srcs scatter).
__global__ __launch_bounds__(256, 2) void k_front(
    const float* __restrict__ x, const _Float16* __restrict__ Wp1,
    _Float16* __restrict__ hs, int n, int gb,
    const int* __restrict__ esrc, const int* __restrict__ edst,
    int* __restrict__ cursor, int* __restrict__ srcs, int E) {
    __shared__ _Float16 Hs[64 * 136];
    const int bb = blockIdx.x;
    if (bb >= gb) {
        int i = (bb - gb) * 256 + threadIdx.x;
        if (i < E) {
            int d = edst[i];
            int p = atomicAdd(&cursor[d], 1);
            if (p < CAP) srcs[(size_t)d * CAP + p] = esrc[i];
        }
        return;
    }
    const int tid = threadIdx.x;
    const int w = tid >> 6, l = tid & 63;
    const int row0 = bb * 64;
    const int arow = row0 + w * 16 + (l & 15);
    const int kq = (l >> 4) << 3;
    const bool ok = arow < n;
    const float* xr = &x[(size_t)arow * DIM + kq];

    f32x4 ah[8];
#pragma unroll
    for (int cb = 0; cb < 8; ++cb) {
        f32x4 z = {0.f, 0.f, 0.f, 0.f};
        ah[cb] = z;
    }

#pragma unroll
    for (int kb = 0; kb < 4; ++kb) {
        float4 v0 = make_float4(0.f, 0.f, 0.f, 0.f), v1 = v0;
        if (ok) {
            v0 = *(const float4*)&xr[kb * 32];
            v1 = *(const float4*)&xr[kb * 32 + 4];
        }
        half8 a;
        a[0] = (_Float16)v0.x; a[1] = (_Float16)v0.y;
        a[2] = (_Float16)v0.z; a[3] = (_Float16)v0.w;
        a[4] = (_Float16)v1.x; a[5] = (_Float16)v1.y;
        a[6] = (_Float16)v1.z; a[7] = (_Float16)v1.w;
#pragma unroll
        for (int cb = 0; cb < 8; ++cb) {
            half8 bf = *(const half8*)&Wp1[((kb * 8 + cb) * 64 + l) * 8];
            ah[cb] = __builtin_amdgcn_mfma_f32_16x16x32_f16(a, bf, ah[cb], 0, 0, 0);
        }
    }
    // hs RAW: accs -> LDS -> coalesced stores (no dinv here; applied in mm2g gather)
    const int orow = w * 16 + ((l >> 4) << 2);
    const int oc = l & 15;
#pragma unroll
    for (int reg = 0; reg < 4; ++reg) {
#pragma unroll
        for (int cb = 0; cb < 8; ++cb)
            Hs[(orow + reg) * 136 + cb * 16 + oc] = (_Float16)ah[cb][reg];
    }
    __syncthreads();
#pragma unroll
    for (int it = 0; it < 4; ++it) {
        int i = it * 256 + tid;          // 1024 chunks of 8 halfs
        int r = i >> 4, c = (i & 15) * 8;
        if (row0 + r < n)
            *(half8*)&hs[(size_t)(row0 + r) * DIM + c] = *(const half8*)&Hs[r * 136 + c];
    }
}

// ---------------- mm2g: gather1 (scaled) + full GEMM2 (x-half computed in-kernel) ----------------
// acc = lrelu(f16(x))@W2[0:128] (streaming GEMM, overlaps gather stalls) + gathered-y@W2[128:256]
__global__ __launch_bounds__(256, 2) void k_mm2g(
    const float* __restrict__ x, const _Float16* __restrict__ hs,
    const int* __restrict__ cursor, const int* __restrict__ srcs,
    const float* __restrict__ b1, const _Float16* __restrict__ Wp2,
    _Float16* __restrict__ hs2, int n) {
    __shared__ _Float16 LS[64 * 136];  // Af = first 8192 halfs; reused as Hs after MFMA
    const int tid = threadIdx.x;
    const int w = tid >> 6, l = tid & 63;
    const int g = tid & 15, gid = tid >> 4;
    const int row0 = blockIdx.x * 64;

    f32x4 acc[8];
#pragma unroll
    for (int cb = 0; cb < 8; ++cb) {
        f32x4 z = {0.f, 0.f, 0.f, 0.f};
        acc[cb] = z;
    }

    // gather: 16 lanes per node, hs rows raw -> per-source dinv applied in-loop
#pragma unroll
    for (int it = 0; it < 4; ++it) {
        int node = row0 + it * 16 + gid;
        half8 o = 0;
        if (node < n) {
            int rawc = cursor[node];
            int cnt = rawc > CAP ? CAP : rawc;
            const int* sl = &srcs[(size_t)node * CAP];
            float d = rsqrtf((float)rawc + 1.0f);
            half8 h = *(const half8*)&hs[(size_t)node * DIM + g * 8];
            float a[8];
#pragma unroll
            for (int e = 0; e < 8; ++e) a[e] = (float)h[e] * d;   // self term: h*dinv(node)
            gather_sum_scaled(hs, cursor, sl, cnt, g, n, a);
            const float4 bb0 = *(const float4*)&b1[g * 8];
            const float4 bb1 = *(const float4*)&b1[g * 8 + 4];
            o[0] = (_Float16)lrelu(fmaf(a[0], d, bb0.x));
            o[1] = (_Float16)lrelu(fmaf(a[1], d, bb0.y));
            o[2] = (_Float16)lrelu(fmaf(a[2], d, bb0.z));
            o[3] = (_Float16)lrelu(fmaf(a[3], d, bb0.w));
            o[4] = (_Float16)lrelu(fmaf(a[4], d, bb1.x));
            o[5] = (_Float16)lrelu(fmaf(a[5], d, bb1.y));
            o[6] = (_Float16)lrelu(fmaf(a[6], d, bb1.z));
            o[7] = (_Float16)lrelu(fmaf(a[7], d, bb1.w));
        }
        // A-frag write: frag = it*4 + (g>>2); lane-in-frag = (g&3)*16 + gid  (row m = gid)
        *(half8*)&LS[(((it * 4 + (g >> 2)) * 64) + (g & 3) * 16 + gid) * 8] = o;
    }

    // x-half GEMM: acc += lrelu(f16(x_tile)) @ W2[0:128,:]  (same math as old P, minus f16 round-trip)
    {
        const int arow = row0 + w * 16 + (l & 15);
        const int kq = (l >> 4) << 3;
        const bool ok = arow < n;
        const float* xr = &x[(size_t)arow * DIM + kq];
#pragma unroll
        for (int kb = 0; kb < 4; ++kb) {
            float4 v0 = make_float4(0.f, 0.f, 0.f, 0.f), v1 = v0;
            if (ok) {
                v0 = *(const float4*)&xr[kb * 32];
                v1 = *(const float4*)&xr[kb * 32 + 4];
            }
            half8 a, al;
            a[0] = (_Float16)v0.x; a[1] = (_Float16)v0.y;
            a[2] = (_Float16)v0.z; a[3] = (_Float16)v0.w;
            a[4] = (_Float16)v1.x; a[5] = (_Float16)v1.y;
            a[6] = (_Float16)v1.z; a[7] = (_Float16)v1.w;
#pragma unroll
            for (int e = 0; e < 8; ++e) {
                _Float16 t = a[e];
                al[e] = (t > (_Float16)0.f) ? t : t * (_Float16)0.01f;
            }
#pragma unroll
            for (int cb = 0; cb < 8; ++cb) {
                half8 bf = *(const half8*)&Wp2[((kb * 8 + cb) * 64 + l) * 8];  // W2 rows 0..127
                acc[cb] = __builtin_amdgcn_mfma_f32_16x16x32_f16(al, bf, acc[cb], 0, 0, 0);
            }
        }
    }
    __syncthreads();

#pragma unroll
    for (int kb = 0; kb < 4; ++kb) {
        half8 a = *(const half8*)&LS[((w * 4 + kb) * 64 + l) * 8];
#pragma unroll
        for (int cb = 0; cb < 8; ++cb) {
            half8 bf = *(const half8*)&Wp2[(((kb + 4) * 8 + cb) * 64 + l) * 8];  // W2 rows 128..255
            acc[cb] = __builtin_amdgcn_mfma_f32_16x16x32_f16(a, bf, acc[cb], 0, 0, 0);
        }
    }
    __syncthreads();  // all waves done reading Af before Hs overwrite
    const int orow = w * 16 + ((l >> 4) << 2);
    const int oc = l & 15;
#pragma unroll
    for (int reg = 0; reg < 4; ++reg) {
        int grow = row0 + orow + reg;
        float d = (grow < n) ? rsqrtf((float)cursor[grow] + 1.0f) : 0.f;
#pragma unroll
        for (int cb = 0; cb < 8; ++cb)
            LS[(orow + reg) * 136 + cb * 16 + oc] = (_Float16)(acc[cb][reg] * d);
    }
    __syncthreads();
#pragma unroll
    for (int it = 0; it < 4; ++it) {
        int i = it * 256 + tid;
        int r = i >> 4, c = (i & 15) * 8;
        if (row0 + r < n)
            *(half8*)&hs2[(size_t)(row0 + r) * DIM + c] = *(const half8*)&LS[r * 136 + c];
    }
}

// ---------------- gather2 + final projection (16-lane groups; hs2 pre-scaled) ----------------
__global__ __launch_bounds__(256) void k_gather2(
    const _Float16* __restrict__ hs2, const int* __restrict__ cursor,
    const int* __restrict__ srcs, const float* __restrict__ b2,
    const float* __restrict__ wout, const float* __restrict__ bout,
    float* __restrict__ out, int n) {
    const int node = blockIdx.x * 16 + (threadIdx.x >> 4);
    const int g = threadIdx.x & 15;
    if (node >= n) return;
    int rawc = cursor[node];
    int cnt = rawc > CAP ? CAP : rawc;
    const int* sl = &srcs[(size_t)node * CAP];
    half8 h = *(const half8*)&hs2[(size_t)node * DIM + g * 8];
    float a[8];
#pragma unroll
    for (int e = 0; e < 8; ++e) a[e] = (float)h[e];
    gather_sum(hs2, sl, cnt, g, n, a);
    float d = rsqrtf((float)rawc + 1.0f);
    const float4 bb0 = *(const float4*)&b2[g * 8];
    const float4 bb1 = *(const float4*)&b2[g * 8 + 4];
    const float4 wv0 = *(const float4*)&wout[g * 8];
    const float4 wv1 = *(const float4*)&wout[g * 8 + 4];
    float s = lrelu(fmaf(a[0], d, bb0.x)) * wv0.x + lrelu(fmaf(a[1], d, bb0.y)) * wv0.y +
              lrelu(fmaf(a[2], d, bb0.z)) * wv0.z + lrelu(fmaf(a[3], d, bb0.w)) * wv0.w +
              lrelu(fmaf(a[4], d, bb1.x)) * wv1.x + lrelu(fmaf(a[5], d, bb1.y)) * wv1.y +
              lrelu(fmaf(a[6], d, bb1.z)) * wv1.z + lrelu(fmaf(a[7], d, bb1.w)) * wv1.w;
#pragma unroll
    for (int off = 8; off > 0; off >>= 1) s += __shfl_down(s, off, 16);
    if (g == 0) out[node] = s + bout[0];
}

extern "C" void kernel_launch(void* const* d_in, const int* in_sizes, int n_in,
                              void* d_out, int out_size, void* d_ws, size_t ws_size,
                              hipStream_t stream) {
    const float* x    = (const float*)d_in[0];
    const int*   ei   = (const int*)d_in[1];
    const float* W1   = (const float*)d_in[2];
    const float* b1   = (const float*)d_in[3];
    const float* W2   = (const float*)d_in[4];
    const float* b2   = (const float*)d_in[5];
    const float* Wout = (const float*)d_in[6];
    const float* bout = (const float*)d_in[7];
    float* out = (float*)d_out;

    const int N = in_sizes[0] / DIM;
    const int E = in_sizes[1] / 2;
    const int* src = ei;      // edge_index[0]
    const int* dst = ei + E;  // edge_index[1]

    const int gb = (N + 63) / 64;
    const long long nx = (long long)N * DIM;

    // workspace — every buffer offset rounded up to 256 B so hs/hs2 rows are line-pair aligned
    // (192 B misalignment made every gathered 256 B row straddle 3 cache lines: FETCH +29%, r9)
    char* wp = (char*)d_ws;
    auto carve = [&](size_t bytes) {
        char* p = wp;
        wp += (bytes + 255) & ~(size_t)255;
        return p;
    };
    size_t Na = ((size_t)N + 63) & ~(size_t)63;   // covers index N (zero-row degree)
    int* cursor   = (int*)carve(Na * 4);
    int* srcs     = (int*)carve(((size_t)N + 1) * CAP * 4);
    _Float16* Wp1 = (_Float16*)carve((size_t)128 * 128 * 2);
    _Float16* Wp2 = (_Float16*)carve((size_t)256 * 128 * 2);
    _Float16* hsb = (_Float16*)carve(((size_t)N + 1) * DIM * 2);  // hs + zero row n
    _Float16* hs2 = (_Float16*)carve(((size_t)N + 1) * DIM * 2);  // hs2 + zero row n

    const int eb = (E + 255) / 256;
    const int na4 = (int)(Na / 4);
    const int nzb = (na4 + 255) / 256;

    k_init<<<nzb + 193, 256, 0, stream>>>(cursor, na4, nzb, W1, Wp1, W2, Wp2,
                                          hsb + nx, hs2 + nx);
    k_front<<<gb + eb, 256, 0, stream>>>(x, Wp1, hsb, N, gb, src, dst, cursor, srcs, E);
    k_mm2g<<<gb, 256, 0, stream>>>(x, hsb, cursor, srcs, b1, Wp2, hs2, N);
    k_gather2<<<(N + 15) / 16, 256, 0, stream>>>(hs2, cursor, srcs, b2, Wout, bout, out, N);
}